// Round 1
// baseline (1087.033 us; speedup 1.0000x reference)
//
#include <hip/hip_runtime.h>
#include <stdint.h>

#define S_LEN 2048
#define BATCH 2
#define DM 768
#define NH 12
#define DKH 64
#define DFF 3072
#define MROWS (BATCH * S_LEN)  // 4096

typedef short bf16x8 __attribute__((ext_vector_type(8)));
typedef float f32x4 __attribute__((ext_vector_type(4)));

__device__ __forceinline__ unsigned short f2b(float f) {
    union { float f; unsigned u; } cv; cv.f = f;
    unsigned u = cv.u;
    unsigned r = (u + 0x7FFFu + ((u >> 16) & 1u)) >> 16;  // RNE
    return (unsigned short)r;
}

// ---------------- conversion: f32 -> bf16 (vectorized) ----------------
__global__ __launch_bounds__(256) void convert_bf16_kernel(
    const float* __restrict__ in, unsigned short* __restrict__ out, int n4) {
    int i = blockIdx.x * 256 + threadIdx.x;
    if (i < n4) {
        float4 v = reinterpret_cast<const float4*>(in)[i];
        ushort4 o;
        o.x = f2b(v.x); o.y = f2b(v.y); o.z = f2b(v.z); o.w = f2b(v.w);
        reinterpret_cast<ushort4*>(out)[i] = o;
    }
}

// ---------------- transpose + convert: W[R][C] f32 -> Wt[C][R] bf16 ----------------
__global__ __launch_bounds__(256) void transpose_bf16_kernel(
    const float* __restrict__ in, unsigned short* __restrict__ out, int R, int C) {
    __shared__ float tile[32][33];
    int c0 = blockIdx.x * 32, r0 = blockIdx.y * 32;
    int tx = threadIdx.x & 31, ty = threadIdx.x >> 5;  // 32 x 8
    #pragma unroll
    for (int i = ty; i < 32; i += 8)
        tile[i][tx] = in[(size_t)(r0 + i) * C + c0 + tx];
    __syncthreads();
    #pragma unroll
    for (int i = ty; i < 32; i += 8)
        out[(size_t)(c0 + i) * R + r0 + tx] = f2b(tile[tx][i]);
}

// ---------------- bf16 MFMA GEMM: C[M,N] = A[M,K] @ Bt[N,K]^T + bias (+res)(+relu) ----------------
// 64x64 block tile, BK=64, 4 waves in 2x2, each wave a 32x32 quad of 16x16x32 MFMAs.
template <int RELU, int RES, int EF32, int EB16>
__global__ __launch_bounds__(256) void gemm_bt(
    const unsigned short* __restrict__ A, const unsigned short* __restrict__ Bt,
    const float* __restrict__ bias, const float* __restrict__ res,
    float* __restrict__ outf, unsigned short* __restrict__ outb,
    int M, int N, int K) {
    __shared__ __align__(16) unsigned short As[64][72];  // pad 72: 2-way bank aliasing only
    __shared__ __align__(16) unsigned short Bs[64][72];
    const int t = threadIdx.x;
    const int wave = t >> 6, lane = t & 63;
    const int wrow = wave >> 1, wcol = wave & 1;
    const int bn = blockIdx.x * 64, bm = blockIdx.y * 64;
    const int lr = lane & 15;            // fragment row (A) / col (B)
    const int lk = (lane >> 4) << 3;     // k offset within fragment

    f32x4 acc[2][2];
    #pragma unroll
    for (int i = 0; i < 2; ++i)
        #pragma unroll
        for (int j = 0; j < 2; ++j) {
            f32x4 z = {0.f, 0.f, 0.f, 0.f};
            acc[i][j] = z;
        }

    const int nkt = K >> 6;
    for (int kt = 0; kt < nkt; ++kt) {
        #pragma unroll
        for (int p = 0; p < 2; ++p) {
            int e = (p * 256 + t) << 3;  // element index in 64x64 tile
            int r = e >> 6, c = e & 63;
            const uint4 av = *reinterpret_cast<const uint4*>(A + (size_t)(bm + r) * K + (kt << 6) + c);
            *reinterpret_cast<uint4*>(&As[r][c]) = av;
            const uint4 bv = *reinterpret_cast<const uint4*>(Bt + (size_t)(bn + r) * K + (kt << 6) + c);
            *reinterpret_cast<uint4*>(&Bs[r][c]) = bv;
        }
        __syncthreads();
        #pragma unroll
        for (int ks = 0; ks < 64; ks += 32) {
            bf16x8 af[2], bfr[2];
            #pragma unroll
            for (int i = 0; i < 2; ++i)
                af[i] = *reinterpret_cast<const bf16x8*>(&As[wrow * 32 + i * 16 + lr][ks + lk]);
            #pragma unroll
            for (int j = 0; j < 2; ++j)
                bfr[j] = *reinterpret_cast<const bf16x8*>(&Bs[wcol * 32 + j * 16 + lr][ks + lk]);
            #pragma unroll
            for (int i = 0; i < 2; ++i)
                #pragma unroll
                for (int j = 0; j < 2; ++j)
                    acc[i][j] = __builtin_amdgcn_mfma_f32_16x16x32_bf16(af[i], bfr[j], acc[i][j], 0, 0, 0);
        }
        __syncthreads();
    }

    // epilogue: C/D layout col = lane&15, row = (lane>>4)*4 + reg
    const int r0 = (lane >> 4) << 2;
    #pragma unroll
    for (int i = 0; i < 2; ++i) {
        #pragma unroll
        for (int j = 0; j < 2; ++j) {
            const int col = bn + wcol * 32 + j * 16 + lr;
            const float bvv = bias[col];
            #pragma unroll
            for (int r = 0; r < 4; ++r) {
                const int row = bm + wrow * 32 + i * 16 + r0 + r;
                float vv = acc[i][j][r] + bvv;
                if (RES) vv += res[(size_t)row * N + col];
                if (RELU) vv = vv > 0.f ? vv : 0.f;
                if (EF32) outf[(size_t)row * N + col] = vv;
                if (EB16) outb[(size_t)row * N + col] = f2b(vv);
            }
        }
    }
}

// ---------------- causal attention, fp32, online softmax ----------------
// Block: 16 query rows of one (b,h); 4 waves x 4 rows. K/V tiles of 64 staged in LDS.
__global__ __launch_bounds__(256) void attn_kernel(
    const float* __restrict__ q, const float* __restrict__ k, const float* __restrict__ v,
    unsigned short* __restrict__ ctx16) {
    __shared__ float Ks[64][65];
    __shared__ float Vs[64][65];
    __shared__ float qs[16][64];
    __shared__ float ps[4][4][64];
    const int t = threadIdx.x, wave = t >> 6, lane = t & 63;
    const int qt = blockIdx.x, bh = blockIdx.y;
    const int b = bh / NH, h = bh % NH;
    const int s0 = qt << 4;
    const size_t base_qkv = ((size_t)b * S_LEN) * DM + h * DKH;

    #pragma unroll
    for (int p = 0; p < 4; ++p) {
        int idx = p * 256 + t;
        int r = idx >> 6, c = idx & 63;
        qs[r][c] = q[base_qkv + (size_t)(s0 + r) * DM + c];
    }
    __syncthreads();

    float m[4], l[4], o[4];
    #pragma unroll
    for (int rr = 0; rr < 4; ++rr) { m[rr] = -3e38f; l[rr] = 0.f; o[rr] = 0.f; }

    const int nt = ((s0 + 15) >> 6) + 1;
    for (int ti = 0; ti < nt; ++ti) {
        const int base = ti << 6;
        #pragma unroll
        for (int p = 0; p < 16; ++p) {
            int idx = p * 256 + t;
            int r = idx >> 6, c = idx & 63;
            size_t g = base_qkv + (size_t)(base + r) * DM + c;
            Ks[r][c] = k[g];
            Vs[r][c] = v[g];
        }
        __syncthreads();

        // scores: lane j holds score vs key (base+j) for each of the wave's 4 rows
        float sc[4];
        #pragma unroll
        for (int rr = 0; rr < 4; ++rr) sc[rr] = 0.f;
        #pragma unroll 4
        for (int d0 = 0; d0 < 64; d0 += 4) {
            const float kv0 = Ks[lane][d0], kv1 = Ks[lane][d0 + 1];
            const float kv2 = Ks[lane][d0 + 2], kv3 = Ks[lane][d0 + 3];
            #pragma unroll
            for (int rr = 0; rr < 4; ++rr) {
                const float4 q4 = *reinterpret_cast<const float4*>(&qs[wave * 4 + rr][d0]);
                sc[rr] += q4.x * kv0 + q4.y * kv1 + q4.z * kv2 + q4.w * kv3;
            }
        }
        const int kg = base + lane;
        #pragma unroll
        for (int rr = 0; rr < 4; ++rr) {
            const int s_row = s0 + wave * 4 + rr;
            const bool valid = (kg <= s_row);
            float s = valid ? sc[rr] * 0.125f : -3e38f;
            float tm = s;
            #pragma unroll
            for (int off = 32; off > 0; off >>= 1) tm = fmaxf(tm, __shfl_xor(tm, off));
            const float mn = fmaxf(m[rr], tm);
            const float corr = __expf(m[rr] - mn);
            const float pj = valid ? __expf(s - mn) : 0.f;
            float ts = pj;
            #pragma unroll
            for (int off = 32; off > 0; off >>= 1) ts += __shfl_xor(ts, off);
            l[rr] = l[rr] * corr + ts;
            o[rr] *= corr;
            m[rr] = mn;
            ps[wave][rr][lane] = pj;
        }
        // PV: lane = output dim, broadcast p via LDS float4
        #pragma unroll 4
        for (int j0 = 0; j0 < 64; j0 += 4) {
            const float v0 = Vs[j0][lane], v1 = Vs[j0 + 1][lane];
            const float v2 = Vs[j0 + 2][lane], v3 = Vs[j0 + 3][lane];
            #pragma unroll
            for (int rr = 0; rr < 4; ++rr) {
                const float4 p4 = *reinterpret_cast<const float4*>(&ps[wave][rr][j0]);
                o[rr] += p4.x * v0 + p4.y * v1 + p4.z * v2 + p4.w * v3;
            }
        }
        __syncthreads();
    }
    #pragma unroll
    for (int rr = 0; rr < 4; ++rr) {
        const int s_row = s0 + wave * 4 + rr;
        ctx16[base_qkv + (size_t)s_row * DM + lane] = f2b(o[rr] / l[rr]);
    }
}

// ---------------- row LayerNorm (in-place capable), optional bf16 copy ----------------
template <int EB16>
__global__ __launch_bounds__(256) void layernorm_kernel(
    const float* __restrict__ in, const float* __restrict__ gam, const float* __restrict__ bet,
    float* __restrict__ outf, unsigned short* __restrict__ outb) {
    __shared__ float red[8];
    const int row = blockIdx.x, t = threadIdx.x;
    const int wave = t >> 6, lane = t & 63;
    const float* p = in + (size_t)row * DM;
    const float v0 = p[t], v1 = p[t + 256], v2 = p[t + 512];
    float s = v0 + v1 + v2;
    float sq = v0 * v0 + v1 * v1 + v2 * v2;
    #pragma unroll
    for (int off = 32; off > 0; off >>= 1) { s += __shfl_xor(s, off); sq += __shfl_xor(sq, off); }
    if (lane == 0) { red[wave] = s; red[wave + 4] = sq; }
    __syncthreads();
    s = red[0] + red[1] + red[2] + red[3];
    sq = red[4] + red[5] + red[6] + red[7];
    const float mu = s * (1.f / DM);
    const float var = sq * (1.f / DM) - mu * mu;
    const float rs = rsqrtf(var + 1e-5f);
    #pragma unroll
    for (int i = 0; i < 3; ++i) {
        const int c = t + i * 256;
        const float vv = (i == 0 ? v0 : (i == 1 ? v1 : v2));
        const float y = (vv - mu) * rs * gam[c] + bet[c];
        outf[(size_t)row * DM + c] = y;
        if (EB16) outb[(size_t)row * DM + c] = f2b(y);
    }
}

extern "C" void kernel_launch(void* const* d_in, const int* in_sizes, int n_in,
                              void* d_out, int out_size, void* d_ws, size_t ws_size,
                              hipStream_t stream) {
    const float* x   = (const float*)d_in[0];
    const float* wq  = (const float*)d_in[1];
    const float* bq  = (const float*)d_in[2];
    const float* wk  = (const float*)d_in[3];
    const float* bk  = (const float*)d_in[4];
    const float* wv  = (const float*)d_in[5];
    const float* bv  = (const float*)d_in[6];
    const float* wo  = (const float*)d_in[7];
    const float* bo  = (const float*)d_in[8];
    const float* w1  = (const float*)d_in[9];
    const float* b1  = (const float*)d_in[10];
    const float* w2  = (const float*)d_in[11];
    const float* b2  = (const float*)d_in[12];
    const float* g1  = (const float*)d_in[13];
    const float* be1 = (const float*)d_in[14];
    const float* g2  = (const float*)d_in[15];
    const float* be2 = (const float*)d_in[16];

    char* wp = (char*)d_ws;
    auto alloc = [&](size_t bytes) -> void* {
        void* r = (void*)wp;
        wp += (bytes + 255) & ~(size_t)255;
        return r;
    };
    const int M = MROWS;
    unsigned short* x16  = (unsigned short*)alloc((size_t)M * DM * 2);
    unsigned short* wq16 = (unsigned short*)alloc((size_t)DM * DM * 2);
    unsigned short* wk16 = (unsigned short*)alloc((size_t)DM * DM * 2);
    unsigned short* wv16 = (unsigned short*)alloc((size_t)DM * DM * 2);
    unsigned short* wo16 = (unsigned short*)alloc((size_t)DM * DM * 2);
    unsigned short* w116 = (unsigned short*)alloc((size_t)DM * DFF * 2);
    unsigned short* w216 = (unsigned short*)alloc((size_t)DM * DFF * 2);
    float* qf = (float*)alloc((size_t)M * DM * 4);
    float* kf = (float*)alloc((size_t)M * DM * 4);
    float* vf = (float*)alloc((size_t)M * DM * 4);
    unsigned short* ctx16 = (unsigned short*)alloc((size_t)M * DM * 2);
    float* y1 = (float*)alloc((size_t)M * DM * 4);
    // dead-buffer reuse: ff1 bf16 [M, DFF] fits in q/k/v region; x1 bf16 in ctx16
    unsigned short* ff116 = (unsigned short*)qf;
    unsigned short* x116  = ctx16;

    // conversions (per-call; no cached state allowed)
    convert_bf16_kernel<<<(M * DM / 4 + 255) / 256, 256, 0, stream>>>(x, x16, M * DM / 4);
    transpose_bf16_kernel<<<dim3(DM / 32, DM / 32), 256, 0, stream>>>(wq, wq16, DM, DM);
    transpose_bf16_kernel<<<dim3(DM / 32, DM / 32), 256, 0, stream>>>(wk, wk16, DM, DM);
    transpose_bf16_kernel<<<dim3(DM / 32, DM / 32), 256, 0, stream>>>(wv, wv16, DM, DM);
    transpose_bf16_kernel<<<dim3(DM / 32, DM / 32), 256, 0, stream>>>(wo, wo16, DM, DM);
    transpose_bf16_kernel<<<dim3(DFF / 32, DM / 32), 256, 0, stream>>>(w1, w116, DM, DFF);
    transpose_bf16_kernel<<<dim3(DM / 32, DFF / 32), 256, 0, stream>>>(w2, w216, DFF, DM);

    // QKV projections -> fp32 [B,S,H*dk]
    gemm_bt<0, 0, 1, 0><<<dim3(DM / 64, M / 64), 256, 0, stream>>>(x16, wq16, bq, nullptr, qf, nullptr, M, DM, DM);
    gemm_bt<0, 0, 1, 0><<<dim3(DM / 64, M / 64), 256, 0, stream>>>(x16, wk16, bk, nullptr, kf, nullptr, M, DM, DM);
    gemm_bt<0, 0, 1, 0><<<dim3(DM / 64, M / 64), 256, 0, stream>>>(x16, wv16, bv, nullptr, vf, nullptr, M, DM, DM);

    // causal attention -> ctx bf16
    attn_kernel<<<dim3(S_LEN / 16, BATCH * NH), 256, 0, stream>>>(qf, kf, vf, ctx16);

    // out proj + residual(x) -> y1 ; LN1 in-place + bf16 copy
    gemm_bt<0, 1, 1, 0><<<dim3(DM / 64, M / 64), 256, 0, stream>>>(ctx16, wo16, bo, x, y1, nullptr, M, DM, DM);
    layernorm_kernel<1><<<M, 256, 0, stream>>>(y1, g1, be1, y1, x116);

    // FFN
    gemm_bt<1, 0, 0, 1><<<dim3(DFF / 64, M / 64), 256, 0, stream>>>(x116, w116, b1, nullptr, nullptr, ff116, M, DFF, DM);
    gemm_bt<0, 1, 1, 0><<<dim3(DM / 64, M / 64), 256, 0, stream>>>(ff116, w216, b2, y1, (float*)d_out, nullptr, M, DM, DFF);
    layernorm_kernel<0><<<M, 256, 0, stream>>>((float*)d_out, g2, be2, (float*)d_out, nullptr);
}

// Round 2
// 338.564 us; speedup vs baseline: 3.2107x; 3.2107x over previous
//
#include <hip/hip_runtime.h>
#include <stdint.h>

#define S_LEN 2048
#define BATCH 2
#define DM 768
#define NH 12
#define DKH 64
#define DFF 3072
#define MROWS (BATCH * S_LEN)  // 4096

typedef short bf16x8 __attribute__((ext_vector_type(8)));
typedef float f32x4 __attribute__((ext_vector_type(4)));

__device__ __forceinline__ unsigned short f2b(float f) {
    union { float f; unsigned u; } cv; cv.f = f;
    unsigned u = cv.u;
    unsigned r = (u + 0x7FFFu + ((u >> 16) & 1u)) >> 16;  // RNE
    return (unsigned short)r;
}

// ---------------- conversion: f32 -> bf16 (vectorized) ----------------
__global__ __launch_bounds__(256) void convert_bf16_kernel(
    const float* __restrict__ in, unsigned short* __restrict__ out, int n4) {
    int i = blockIdx.x * 256 + threadIdx.x;
    if (i < n4) {
        float4 v = reinterpret_cast<const float4*>(in)[i];
        ushort4 o;
        o.x = f2b(v.x); o.y = f2b(v.y); o.z = f2b(v.z); o.w = f2b(v.w);
        reinterpret_cast<ushort4*>(out)[i] = o;
    }
}

// ---------------- transpose + convert: W[R][C] f32 -> Wt[C][R] bf16 ----------------
__global__ __launch_bounds__(256) void transpose_bf16_kernel(
    const float* __restrict__ in, unsigned short* __restrict__ out, int R, int C) {
    __shared__ float tile[32][33];
    int c0 = blockIdx.x * 32, r0 = blockIdx.y * 32;
    int tx = threadIdx.x & 31, ty = threadIdx.x >> 5;  // 32 x 8
    #pragma unroll
    for (int i = ty; i < 32; i += 8)
        tile[i][tx] = in[(size_t)(r0 + i) * C + c0 + tx];
    __syncthreads();
    #pragma unroll
    for (int i = ty; i < 32; i += 8)
        out[(size_t)(c0 + i) * R + r0 + tx] = f2b(tile[tx][i]);
}

// ---------------- bf16 MFMA GEMM: C[M,N] = A[M,K] @ Bt[N,K]^T + bias (+res)(+relu) ----------------
// 64x64 block tile, BK=64, 4 waves in 2x2, each wave a 32x32 quad of 16x16x32 MFMAs.
// OMODE 0: flat [M,N] out (EF32/EB16). OMODE 1: bf16 head-split [B,H,S,dk] * oscale.
// OMODE 2: bf16 head-split transposed [B,H,dk,S] (packed 4-row stores).
template <int RELU, int RES, int EF32, int EB16, int OMODE>
__global__ __launch_bounds__(256) void gemm_bt(
    const unsigned short* __restrict__ A, const unsigned short* __restrict__ Bt,
    const float* __restrict__ bias, const float* __restrict__ res,
    float* __restrict__ outf, unsigned short* __restrict__ outb,
    int M, int N, int K, float oscale) {
    __shared__ __align__(16) unsigned short As[64][72];
    __shared__ __align__(16) unsigned short Bs[64][72];
    const int t = threadIdx.x;
    const int wave = t >> 6, lane = t & 63;
    const int wrow = wave >> 1, wcol = wave & 1;
    const int bn = blockIdx.x * 64, bm = blockIdx.y * 64;
    const int lr = lane & 15;
    const int lk = (lane >> 4) << 3;

    f32x4 acc[2][2];
    #pragma unroll
    for (int i = 0; i < 2; ++i)
        #pragma unroll
        for (int j = 0; j < 2; ++j) {
            f32x4 z = {0.f, 0.f, 0.f, 0.f};
            acc[i][j] = z;
        }

    const int nkt = K >> 6;
    for (int kt = 0; kt < nkt; ++kt) {
        #pragma unroll
        for (int p = 0; p < 2; ++p) {
            int e = (p * 256 + t) << 3;
            int r = e >> 6, c = e & 63;
            const uint4 av = *reinterpret_cast<const uint4*>(A + (size_t)(bm + r) * K + (kt << 6) + c);
            *reinterpret_cast<uint4*>(&As[r][c]) = av;
            const uint4 bv = *reinterpret_cast<const uint4*>(Bt + (size_t)(bn + r) * K + (kt << 6) + c);
            *reinterpret_cast<uint4*>(&Bs[r][c]) = bv;
        }
        __syncthreads();
        #pragma unroll
        for (int ks = 0; ks < 64; ks += 32) {
            bf16x8 af[2], bfr[2];
            #pragma unroll
            for (int i = 0; i < 2; ++i)
                af[i] = *reinterpret_cast<const bf16x8*>(&As[wrow * 32 + i * 16 + lr][ks + lk]);
            #pragma unroll
            for (int j = 0; j < 2; ++j)
                bfr[j] = *reinterpret_cast<const bf16x8*>(&Bs[wcol * 32 + j * 16 + lr][ks + lk]);
            #pragma unroll
            for (int i = 0; i < 2; ++i)
                #pragma unroll
                for (int j = 0; j < 2; ++j)
                    acc[i][j] = __builtin_amdgcn_mfma_f32_16x16x32_bf16(af[i], bfr[j], acc[i][j], 0, 0, 0);
        }
        __syncthreads();
    }

    const int r0 = (lane >> 4) << 2;
    #pragma unroll
    for (int i = 0; i < 2; ++i) {
        #pragma unroll
        for (int j = 0; j < 2; ++j) {
            const int col = bn + wcol * 32 + j * 16 + lr;
            const float bvv = bias[col];
            if (OMODE == 2) {
                const int row_base = bm + wrow * 32 + i * 16 + r0;
                const int b = row_base >> 11, s = row_base & 2047;
                const int h = col >> 6, d = col & 63;
                ushort4 w;
                w.x = f2b((acc[i][j][0] + bvv) * oscale);
                w.y = f2b((acc[i][j][1] + bvv) * oscale);
                w.z = f2b((acc[i][j][2] + bvv) * oscale);
                w.w = f2b((acc[i][j][3] + bvv) * oscale);
                *reinterpret_cast<ushort4*>(outb + (((size_t)(b * NH + h) * DKH) + d) * S_LEN + s) = w;
            } else {
                #pragma unroll
                for (int r = 0; r < 4; ++r) {
                    const int row = bm + wrow * 32 + i * 16 + r0 + r;
                    float vv = acc[i][j][r] + bvv;
                    if (OMODE == 1) {
                        const int b = row >> 11, s = row & 2047;
                        const int h = col >> 6, d = col & 63;
                        outb[(((size_t)(b * NH + h) * S_LEN) + s) * DKH + d] = f2b(vv * oscale);
                    } else {
                        if (RES) vv += res[(size_t)row * N + col];
                        if (RELU) vv = vv > 0.f ? vv : 0.f;
                        if (EF32) outf[(size_t)row * N + col] = vv;
                        if (EB16) outb[(size_t)row * N + col] = f2b(vv);
                    }
                }
            }
        }
    }
}

// ---------------- MFMA causal flash attention ----------------
// Block: 64 q-rows of one (b,h); 4 waves x 16 rows. KV tiles of 64.
// Q pre-scaled by 0.125*log2(e): softmax in exp2 domain.
// S^T = mfma(K, Q): col(lane&15) = q, row = key -> cheap per-lane softmax.
__global__ __launch_bounds__(256) void attn_mfma_kernel(
    const unsigned short* __restrict__ q16,   // [B,H,S,64]
    const unsigned short* __restrict__ k16,   // [B,H,S,64]
    const unsigned short* __restrict__ vt16,  // [B,H,64,S]
    unsigned short* __restrict__ ctx16) {     // [B,S,DM]
    __shared__ __align__(16) unsigned short Qs[64 * 64];
    __shared__ __align__(16) unsigned short Ks[64 * 64];
    __shared__ __align__(16) unsigned short Vt[64 * 64];
    __shared__ __align__(16) unsigned short Pl[4][16][72];
    const int t = threadIdx.x, wave = t >> 6, lane = t & 63;
    const int qb = (gridDim.x - 1) - blockIdx.x;  // heavy blocks first
    const int bh = blockIdx.y;
    const int b = bh / NH, h = bh % NH;
    const int s0 = qb << 6;
    const size_t hbase = (size_t)bh * S_LEN * DKH;
    const int lr = lane & 15;
    const int g4 = (lane >> 4) << 2;
    const int lk8 = (lane >> 4) << 3;
    const int qg = s0 + wave * 16 + lr;  // this lane's softmax row (global s)

    // stage Q (swizzled: byte ^= ((row&7)<<4))
    {
        const char* gq = (const char*)(q16 + hbase + (size_t)s0 * DKH);
        #pragma unroll
        for (int p = 0; p < 2; ++p) {
            int o = (p * 256 + t) * 16;
            int sw = o ^ (((o >> 7) & 7) << 4);
            *reinterpret_cast<uint4*>((char*)Qs + sw) = *reinterpret_cast<const uint4*>(gq + o);
        }
    }

    float mst = -3e38f, lst = 0.f;
    f32x4 acc[4];
    #pragma unroll
    for (int j = 0; j < 4; ++j) { f32x4 z = {0.f, 0.f, 0.f, 0.f}; acc[j] = z; }

    const int nt = qb + 1;
    for (int kt = 0; kt < nt; ++kt) {
        __syncthreads();  // previous tile's LDS reads done (also covers Q stage at kt=0)
        {
            const char* gk = (const char*)(k16 + hbase + (((size_t)kt) << 6) * DKH);
            #pragma unroll
            for (int p = 0; p < 2; ++p) {
                int o = (p * 256 + t) * 16;
                int sw = o ^ (((o >> 7) & 7) << 4);
                *reinterpret_cast<uint4*>((char*)Ks + sw) = *reinterpret_cast<const uint4*>(gk + o);
            }
            const char* gv = (const char*)vt16 + (hbase + ((size_t)kt << 6)) * 2;
            #pragma unroll
            for (int p = 0; p < 2; ++p) {
                int o = (p * 256 + t) * 16;
                int row = (o >> 7) & 63;
                int sw = o ^ ((row & 7) << 4);
                *reinterpret_cast<uint4*>((char*)Vt + sw) =
                    *reinterpret_cast<const uint4*>(gv + (size_t)row * (S_LEN * 2) + (o & 127));
            }
        }
        __syncthreads();

        // S^T = K * Q^T
        f32x4 sc[4];
        #pragma unroll
        for (int j = 0; j < 4; ++j) { f32x4 z = {0.f, 0.f, 0.f, 0.f}; sc[j] = z; }
        #pragma unroll
        for (int ks = 0; ks < 64; ks += 32) {
            const int qrow = wave * 16 + lr;
            bf16x8 qa = *reinterpret_cast<const bf16x8*>(
                (const char*)Qs + (((qrow * 64 + ks + lk8) * 2) ^ ((qrow & 7) << 4)));
            #pragma unroll
            for (int j = 0; j < 4; ++j) {
                const int krow = j * 16 + lr;
                bf16x8 ka = *reinterpret_cast<const bf16x8*>(
                    (const char*)Ks + (((krow * 64 + ks + lk8) * 2) ^ ((krow & 7) << 4)));
                sc[j] = __builtin_amdgcn_mfma_f32_16x16x32_bf16(ka, qa, sc[j], 0, 0, 0);
            }
        }

        // online softmax (exp2 domain), per-lane row q = wave*16+lr
        float pf_[4][4];
        float tm = -3e38f;
        #pragma unroll
        for (int j = 0; j < 4; ++j)
            #pragma unroll
            for (int r = 0; r < 4; ++r) {
                const int kg = (kt << 6) + j * 16 + g4 + r;
                const float v = (kg <= qg) ? sc[j][r] : -3e38f;
                pf_[j][r] = v;
                tm = fmaxf(tm, v);
            }
        tm = fmaxf(tm, __shfl_xor(tm, 16));
        tm = fmaxf(tm, __shfl_xor(tm, 32));
        const float mn = fmaxf(mst, tm);
        const float corr = exp2f(mst - mn);
        float ts = 0.f;
        #pragma unroll
        for (int j = 0; j < 4; ++j)
            #pragma unroll
            for (int r = 0; r < 4; ++r) {
                const float p = exp2f(pf_[j][r] - mn);
                pf_[j][r] = p;
                ts += p;
            }
        ts += __shfl_xor(ts, 16);
        ts += __shfl_xor(ts, 32);
        lst = lst * corr + ts;
        mst = mn;
        #pragma unroll
        for (int r = 0; r < 4; ++r) {
            const float cr = __shfl(corr, g4 + r);
            #pragma unroll
            for (int j = 0; j < 4; ++j) acc[j][r] *= cr;
        }
        // pack P -> per-wave LDS [q=lr][key] (4 consecutive keys per b64 write)
        #pragma unroll
        for (int j = 0; j < 4; ++j) {
            ushort4 w;
            w.x = f2b(pf_[j][0]); w.y = f2b(pf_[j][1]);
            w.z = f2b(pf_[j][2]); w.w = f2b(pf_[j][3]);
            *reinterpret_cast<ushort4*>(&Pl[wave][lr][j * 16 + g4]) = w;
        }
        // PV: out[q][d] += P[q][key] * Vt[d][key]^T
        #pragma unroll
        for (int kc = 0; kc < 64; kc += 32) {
            bf16x8 pa = *reinterpret_cast<const bf16x8*>(&Pl[wave][lr][kc + lk8]);
            #pragma unroll
            for (int j = 0; j < 4; ++j) {
                const int vrow = j * 16 + lr;
                bf16x8 vb = *reinterpret_cast<const bf16x8*>(
                    (const char*)Vt + (((vrow * 64 + kc + lk8) * 2) ^ ((vrow & 7) << 4)));
                acc[j] = __builtin_amdgcn_mfma_f32_16x16x32_bf16(pa, vb, acc[j], 0, 0, 0);
            }
        }
    }

    const float li = 1.f / lst;
    #pragma unroll
    for (int r = 0; r < 4; ++r) {
        const float lrc = __shfl(li, g4 + r);
        const int srow = s0 + wave * 16 + g4 + r;
        #pragma unroll
        for (int j = 0; j < 4; ++j) {
            ctx16[((size_t)b * S_LEN + srow) * DM + h * DKH + j * 16 + lr] =
                f2b(acc[j][r] * lrc);
        }
    }
}

// ---------------- row LayerNorm, optional bf16 copy ----------------
template <int EB16>
__global__ __launch_bounds__(256) void layernorm_kernel(
    const float* __restrict__ in, const float* __restrict__ gam, const float* __restrict__ bet,
    float* __restrict__ outf, unsigned short* __restrict__ outb) {
    __shared__ float red[8];
    const int row = blockIdx.x, t = threadIdx.x;
    const int wave = t >> 6, lane = t & 63;
    const float* p = in + (size_t)row * DM;
    const float v0 = p[t], v1 = p[t + 256], v2 = p[t + 512];
    float s = v0 + v1 + v2;
    float sq = v0 * v0 + v1 * v1 + v2 * v2;
    #pragma unroll
    for (int off = 32; off > 0; off >>= 1) { s += __shfl_xor(s, off); sq += __shfl_xor(sq, off); }
    if (lane == 0) { red[wave] = s; red[wave + 4] = sq; }
    __syncthreads();
    s = red[0] + red[1] + red[2] + red[3];
    sq = red[4] + red[5] + red[6] + red[7];
    const float mu = s * (1.f / DM);
    const float var = sq * (1.f / DM) - mu * mu;
    const float rs = rsqrtf(var + 1e-5f);
    #pragma unroll
    for (int i = 0; i < 3; ++i) {
        const int c = t + i * 256;
        const float vv = (i == 0 ? v0 : (i == 1 ? v1 : v2));
        const float y = (vv - mu) * rs * gam[c] + bet[c];
        outf[(size_t)row * DM + c] = y;
        if (EB16) outb[(size_t)row * DM + c] = f2b(y);
    }
}

extern "C" void kernel_launch(void* const* d_in, const int* in_sizes, int n_in,
                              void* d_out, int out_size, void* d_ws, size_t ws_size,
                              hipStream_t stream) {
    const float* x   = (const float*)d_in[0];
    const float* wq  = (const float*)d_in[1];
    const float* bq  = (const float*)d_in[2];
    const float* wk  = (const float*)d_in[3];
    const float* bk  = (const float*)d_in[4];
    const float* wv  = (const float*)d_in[5];
    const float* bv  = (const float*)d_in[6];
    const float* wo  = (const float*)d_in[7];
    const float* bo  = (const float*)d_in[8];
    const float* w1  = (const float*)d_in[9];
    const float* b1  = (const float*)d_in[10];
    const float* w2  = (const float*)d_in[11];
    const float* b2  = (const float*)d_in[12];
    const float* g1  = (const float*)d_in[13];
    const float* be1 = (const float*)d_in[14];
    const float* g2  = (const float*)d_in[15];
    const float* be2 = (const float*)d_in[16];

    char* wp = (char*)d_ws;
    auto alloc = [&](size_t bytes) -> void* {
        void* r = (void*)wp;
        wp += (bytes + 255) & ~(size_t)255;
        return r;
    };
    const int M = MROWS;
    unsigned short* wq16 = (unsigned short*)alloc((size_t)DM * DM * 2);
    unsigned short* wk16 = (unsigned short*)alloc((size_t)DM * DM * 2);
    unsigned short* wv16 = (unsigned short*)alloc((size_t)DM * DM * 2);
    unsigned short* wo16 = (unsigned short*)alloc((size_t)DM * DM * 2);
    unsigned short* w116 = (unsigned short*)alloc((size_t)DM * DFF * 2);
    unsigned short* w216 = (unsigned short*)alloc((size_t)DM * DFF * 2);
    unsigned short* ctx16 = (unsigned short*)alloc((size_t)M * DM * 2);
    float* y1 = (float*)alloc((size_t)M * DM * 4);
    unsigned short* x16  = (unsigned short*)alloc((size_t)M * DM * 2);
    unsigned short* q16  = (unsigned short*)alloc((size_t)M * DM * 2);
    unsigned short* k16  = (unsigned short*)alloc((size_t)M * DM * 2);
    unsigned short* vt16 = (unsigned short*)alloc((size_t)M * DM * 2);
    // aliases over dead regions:
    unsigned short* ff116 = x16;    // [M,DFF] bf16 = 4 * [M,DM] bf16 (x16..vt16 contiguous)
    unsigned short* x116  = ctx16;  // LN1 bf16 output

    convert_bf16_kernel<<<(M * DM / 4 + 255) / 256, 256, 0, stream>>>(x, x16, M * DM / 4);
    transpose_bf16_kernel<<<dim3(DM / 32, DM / 32), 256, 0, stream>>>(wq, wq16, DM, DM);
    transpose_bf16_kernel<<<dim3(DM / 32, DM / 32), 256, 0, stream>>>(wk, wk16, DM, DM);
    transpose_bf16_kernel<<<dim3(DM / 32, DM / 32), 256, 0, stream>>>(wv, wv16, DM, DM);
    transpose_bf16_kernel<<<dim3(DM / 32, DM / 32), 256, 0, stream>>>(wo, wo16, DM, DM);
    transpose_bf16_kernel<<<dim3(DFF / 32, DM / 32), 256, 0, stream>>>(w1, w116, DM, DFF);
    transpose_bf16_kernel<<<dim3(DM / 32, DFF / 32), 256, 0, stream>>>(w2, w216, DFF, DM);

    // QKV projections -> bf16 head-split; Q pre-scaled by 0.125*log2(e)
    const float QSCALE = 0.125f * 1.44269504088896f;
    gemm_bt<0, 0, 0, 1, 1><<<dim3(DM / 64, M / 64), 256, 0, stream>>>(x16, wq16, bq, nullptr, nullptr, q16, M, DM, DM, QSCALE);
    gemm_bt<0, 0, 0, 1, 1><<<dim3(DM / 64, M / 64), 256, 0, stream>>>(x16, wk16, bk, nullptr, nullptr, k16, M, DM, DM, 1.f);
    gemm_bt<0, 0, 0, 1, 2><<<dim3(DM / 64, M / 64), 256, 0, stream>>>(x16, wv16, bv, nullptr, nullptr, vt16, M, DM, DM, 1.f);

    attn_mfma_kernel<<<dim3(S_LEN / 64, BATCH * NH), 256, 0, stream>>>(q16, k16, vt16, ctx16);

    gemm_bt<0, 1, 1, 0, 0><<<dim3(DM / 64, M / 64), 256, 0, stream>>>(ctx16, wo16, bo, x, y1, nullptr, M, DM, DM, 1.f);
    layernorm_kernel<1><<<M, 256, 0, stream>>>(y1, g1, be1, y1, x116);

    gemm_bt<1, 0, 0, 1, 0><<<dim3(DFF / 64, M / 64), 256, 0, stream>>>(x116, w116, b1, nullptr, nullptr, ff116, M, DFF, DM, 1.f);
    gemm_bt<0, 1, 1, 0, 0><<<dim3(DM / 64, M / 64), 256, 0, stream>>>(ff116, w216, b2, y1, (float*)d_out, nullptr, M, DM, DFF, 1.f);
    layernorm_kernel<0><<<M, 256, 0, stream>>>((float*)d_out, g2, be2, (float*)d_out, nullptr);
}

// Round 3
// 304.688 us; speedup vs baseline: 3.5677x; 1.1112x over previous
//
#include <hip/hip_runtime.h>
#include <stdint.h>

#define S_LEN 2048
#define BATCH 2
#define DM 768
#define NH 12
#define DKH 64
#define DFF 3072
#define MROWS (BATCH * S_LEN)  // 4096

typedef short bf16x8 __attribute__((ext_vector_type(8)));
typedef float f32x4 __attribute__((ext_vector_type(4)));

__device__ __forceinline__ unsigned short f2b(float f) {
    union { float f; unsigned u; } cv; cv.f = f;
    unsigned u = cv.u;
    unsigned r = (u + 0x7FFFu + ((u >> 16) & 1u)) >> 16;  // RNE
    return (unsigned short)r;
}

__device__ __forceinline__ void gload16(const void* g, void* l) {
    __builtin_amdgcn_global_load_lds(
        (const __attribute__((address_space(1))) unsigned int*)g,
        (__attribute__((address_space(3))) unsigned int*)l, 16, 0, 0);
}

// ---------------- conversion: f32 -> bf16 (vectorized) ----------------
__global__ __launch_bounds__(256) void convert_bf16_kernel(
    const float* __restrict__ in, unsigned short* __restrict__ out, int n4) {
    int i = blockIdx.x * 256 + threadIdx.x;
    if (i < n4) {
        float4 v = reinterpret_cast<const float4*>(in)[i];
        ushort4 o;
        o.x = f2b(v.x); o.y = f2b(v.y); o.z = f2b(v.z); o.w = f2b(v.w);
        reinterpret_cast<ushort4*>(out)[i] = o;
    }
}

// ---------------- transpose + convert: W[R][C] f32 -> Wt[C][R] bf16 ----------------
__global__ __launch_bounds__(256) void transpose_bf16_kernel(
    const float* __restrict__ in, unsigned short* __restrict__ out, int R, int C) {
    __shared__ float tile[32][33];
    int c0 = blockIdx.x * 32, r0 = blockIdx.y * 32;
    int tx = threadIdx.x & 31, ty = threadIdx.x >> 5;  // 32 x 8
    #pragma unroll
    for (int i = ty; i < 32; i += 8)
        tile[i][tx] = in[(size_t)(r0 + i) * C + c0 + tx];
    __syncthreads();
    #pragma unroll
    for (int i = ty; i < 32; i += 8)
        out[(size_t)(c0 + i) * R + r0 + tx] = f2b(tile[tx][i]);
}

// ============ m97-structure GEMM: 128x128 tile, BK=64, global_load_lds staging ============
// A[M,K] bf16, Bt[N,K] bf16. 4 waves in 2x2, each wave 64x64 (4x4 16x16x32 MFMA frags).
#define GEMM_STAGE(kt)                                                                   \
    {                                                                                    \
        const char* ga = (const char*)(A + (size_t)bm * K + ((kt) << 6));                \
        const char* gb = (const char*)(Bt + (size_t)bn * K + ((kt) << 6));               \
        const size_t K2 = (size_t)K * 2;                                                 \
        _Pragma("unroll")                                                                \
        for (int p = 0; p < 4; ++p)                                                      \
            gload16(ga + (size_t)(srow + p * 32) * K2 + scol,                            \
                    (char*)As + p * 4096 + t * 16);                                      \
        _Pragma("unroll")                                                                \
        for (int p = 0; p < 4; ++p)                                                      \
            gload16(gb + (size_t)(srow + p * 32) * K2 + scol,                            \
                    (char*)Bs + p * 4096 + t * 16);                                      \
    }

#define GEMM_COMPUTE()                                                                   \
    _Pragma("unroll")                                                                    \
    for (int ks = 0; ks < 64; ks += 32) {                                                \
        bf16x8 af[4], bfv[4];                                                            \
        _Pragma("unroll")                                                                \
        for (int i = 0; i < 4; ++i)                                                      \
            af[i] = *reinterpret_cast<const bf16x8*>(&As[(wrow * 64 + i * 16 + lr) * 64 + ks + lk8]); \
        _Pragma("unroll")                                                                \
        for (int j = 0; j < 4; ++j)                                                      \
            bfv[j] = *reinterpret_cast<const bf16x8*>(&Bs[(wcol * 64 + j * 16 + lr) * 64 + ks + lk8]); \
        _Pragma("unroll")                                                                \
        for (int i = 0; i < 4; ++i)                                                      \
            _Pragma("unroll")                                                            \
            for (int j = 0; j < 4; ++j)                                                  \
                acc[i][j] = __builtin_amdgcn_mfma_f32_16x16x32_bf16(af[i], bfv[j], acc[i][j], 0, 0, 0); \
    }

#define GEMM_PROLOG()                                                                    \
    __shared__ __align__(16) unsigned short As[128 * 64];                                \
    __shared__ __align__(16) unsigned short Bs[128 * 64];                                \
    const int t = threadIdx.x;                                                           \
    const int wave = t >> 6, lane = t & 63;                                              \
    const int wrow = wave >> 1, wcol = wave & 1;                                         \
    const int bn = blockIdx.x * 128, bm = blockIdx.y * 128;                              \
    const int lr = lane & 15;                                                            \
    const int lk8 = (lane >> 4) << 3;                                                    \
    const int srow = t >> 3;          /* staging row 0..31 */                            \
    const int scol = (t & 7) * 16;    /* staging byte col 0..112 */                      \
    f32x4 acc[4][4];                                                                     \
    _Pragma("unroll")                                                                    \
    for (int i = 0; i < 4; ++i)                                                          \
        _Pragma("unroll")                                                                \
        for (int j = 0; j < 4; ++j) { f32x4 z = {0.f, 0.f, 0.f, 0.f}; acc[i][j] = z; }   \
    const int nkt = K >> 6;                                                              \
    for (int kt = 0; kt < nkt; ++kt) {                                                   \
        GEMM_STAGE(kt)                                                                   \
        __syncthreads();                                                                 \
        GEMM_COMPUTE()                                                                   \
        __syncthreads();                                                                 \
    }                                                                                    \
    const int r0 = (lane >> 4) << 2;

// flat epilogue variant
template <int RELU, int RES, int EF32, int EB16>
__global__ __launch_bounds__(256) void gemm128(
    const unsigned short* __restrict__ A, const unsigned short* __restrict__ Bt,
    const float* __restrict__ bias, const float* __restrict__ res,
    float* __restrict__ outf, unsigned short* __restrict__ outb,
    int M, int N, int K) {
    GEMM_PROLOG()
    #pragma unroll
    for (int i = 0; i < 4; ++i) {
        const int row_b = bm + wrow * 64 + i * 16 + r0;
        #pragma unroll
        for (int j = 0; j < 4; ++j) {
            const int col = bn + wcol * 64 + j * 16 + lr;
            const float bvv = bias[col];
            #pragma unroll
            for (int r = 0; r < 4; ++r) {
                float vv = acc[i][j][r] + bvv;
                if (RES) vv += res[(size_t)(row_b + r) * N + col];
                if (RELU) vv = vv > 0.f ? vv : 0.f;
                if (EF32) outf[(size_t)(row_b + r) * N + col] = vv;
                if (EB16) outb[(size_t)(row_b + r) * N + col] = f2b(vv);
            }
        }
    }
}

// fused QKV epilogue: N=2304 = [Q | K | V]; Q scaled, K plain -> [B,H,S,64]; V -> [B,H,64,S]
__global__ __launch_bounds__(256) void gemm128_qkv(
    const unsigned short* __restrict__ A, const unsigned short* __restrict__ Bt,
    const float* __restrict__ bq, const float* __restrict__ bk, const float* __restrict__ bv,
    unsigned short* __restrict__ q16, unsigned short* __restrict__ k16,
    unsigned short* __restrict__ vt16, int M, int N, int K, float qscale) {
    GEMM_PROLOG()
    #pragma unroll
    for (int i = 0; i < 4; ++i) {
        const int row_b = bm + wrow * 64 + i * 16 + r0;
        const int b = row_b >> 11, s = row_b & 2047;
        #pragma unroll
        for (int j = 0; j < 4; ++j) {
            const int col = bn + wcol * 64 + j * 16 + lr;
            const int sec = (col >= 2 * DM) ? 2 : (col >= DM ? 1 : 0);
            const int nc = col - sec * DM;
            const int h = nc >> 6, d = nc & 63;
            const float bvv = (sec == 0 ? bq : (sec == 1 ? bk : bv))[nc];
            if (sec == 2) {
                ushort4 w;
                w.x = f2b(acc[i][j][0] + bvv);
                w.y = f2b(acc[i][j][1] + bvv);
                w.z = f2b(acc[i][j][2] + bvv);
                w.w = f2b(acc[i][j][3] + bvv);
                *reinterpret_cast<ushort4*>(
                    vt16 + (((size_t)(b * NH + h) * DKH) + d) * S_LEN + s) = w;
            } else {
                const float sc = (sec == 0) ? qscale : 1.f;
                unsigned short* dst = (sec == 0) ? q16 : k16;
                #pragma unroll
                for (int r = 0; r < 4; ++r)
                    dst[(((size_t)(b * NH + h) * S_LEN) + s + r) * DKH + d] =
                        f2b((acc[i][j][r] + bvv) * sc);
            }
        }
    }
}

// ---------------- MFMA causal flash attention ----------------
__global__ __launch_bounds__(256) void attn_mfma_kernel(
    const unsigned short* __restrict__ q16,   // [B,H,S,64]
    const unsigned short* __restrict__ k16,   // [B,H,S,64]
    const unsigned short* __restrict__ vt16,  // [B,H,64,S]
    unsigned short* __restrict__ ctx16) {     // [B,S,DM]
    __shared__ __align__(16) unsigned short Qs[64 * 64];
    __shared__ __align__(16) unsigned short Ks[64 * 64];
    __shared__ __align__(16) unsigned short Vt[64 * 64];
    __shared__ __align__(16) unsigned short Pl[4][16][72];
    const int t = threadIdx.x, wave = t >> 6, lane = t & 63;
    const int qb = (gridDim.x - 1) - blockIdx.x;  // heavy blocks first
    const int bh = blockIdx.y;
    const int b = bh / NH, h = bh % NH;
    const int s0 = qb << 6;
    const size_t hbase = (size_t)bh * S_LEN * DKH;
    const int lr = lane & 15;
    const int g4 = (lane >> 4) << 2;
    const int lk8 = (lane >> 4) << 3;
    const int qg = s0 + wave * 16 + lr;

    {
        const char* gq = (const char*)(q16 + hbase + (size_t)s0 * DKH);
        #pragma unroll
        for (int p = 0; p < 2; ++p) {
            int o = (p * 256 + t) * 16;
            int sw = o ^ (((o >> 7) & 7) << 4);
            *reinterpret_cast<uint4*>((char*)Qs + sw) = *reinterpret_cast<const uint4*>(gq + o);
        }
    }

    float mst = -3e38f, lst = 0.f;
    f32x4 acc[4];
    #pragma unroll
    for (int j = 0; j < 4; ++j) { f32x4 z = {0.f, 0.f, 0.f, 0.f}; acc[j] = z; }

    const int nt = qb + 1;
    for (int kt = 0; kt < nt; ++kt) {
        __syncthreads();
        {
            const char* gk = (const char*)(k16 + hbase + (((size_t)kt) << 6) * DKH);
            #pragma unroll
            for (int p = 0; p < 2; ++p) {
                int o = (p * 256 + t) * 16;
                int sw = o ^ (((o >> 7) & 7) << 4);
                *reinterpret_cast<uint4*>((char*)Ks + sw) = *reinterpret_cast<const uint4*>(gk + o);
            }
            const char* gv = (const char*)vt16 + (hbase + ((size_t)kt << 6)) * 2;
            #pragma unroll
            for (int p = 0; p < 2; ++p) {
                int o = (p * 256 + t) * 16;
                int row = (o >> 7) & 63;
                int sw = o ^ ((row & 7) << 4);
                *reinterpret_cast<uint4*>((char*)Vt + sw) =
                    *reinterpret_cast<const uint4*>(gv + (size_t)row * (S_LEN * 2) + (o & 127));
            }
        }
        __syncthreads();

        f32x4 sc[4];
        #pragma unroll
        for (int j = 0; j < 4; ++j) { f32x4 z = {0.f, 0.f, 0.f, 0.f}; sc[j] = z; }
        #pragma unroll
        for (int ks = 0; ks < 64; ks += 32) {
            const int qrow = wave * 16 + lr;
            bf16x8 qa = *reinterpret_cast<const bf16x8*>(
                (const char*)Qs + (((qrow * 64 + ks + lk8) * 2) ^ ((qrow & 7) << 4)));
            #pragma unroll
            for (int j = 0; j < 4; ++j) {
                const int krow = j * 16 + lr;
                bf16x8 ka = *reinterpret_cast<const bf16x8*>(
                    (const char*)Ks + (((krow * 64 + ks + lk8) * 2) ^ ((krow & 7) << 4)));
                sc[j] = __builtin_amdgcn_mfma_f32_16x16x32_bf16(ka, qa, sc[j], 0, 0, 0);
            }
        }

        float pf_[4][4];
        float tm = -3e38f;
        #pragma unroll
        for (int j = 0; j < 4; ++j)
            #pragma unroll
            for (int r = 0; r < 4; ++r) {
                const int kg = (kt << 6) + j * 16 + g4 + r;
                const float v = (kg <= qg) ? sc[j][r] : -3e38f;
                pf_[j][r] = v;
                tm = fmaxf(tm, v);
            }
        tm = fmaxf(tm, __shfl_xor(tm, 16));
        tm = fmaxf(tm, __shfl_xor(tm, 32));
        const float mn = fmaxf(mst, tm);
        const float corr = exp2f(mst - mn);
        float ts = 0.f;
        #pragma unroll
        for (int j = 0; j < 4; ++j)
            #pragma unroll
            for (int r = 0; r < 4; ++r) {
                const float p = exp2f(pf_[j][r] - mn);
                pf_[j][r] = p;
                ts += p;
            }
        ts += __shfl_xor(ts, 16);
        ts += __shfl_xor(ts, 32);
        lst = lst * corr + ts;
        mst = mn;
        #pragma unroll
        for (int r = 0; r < 4; ++r) {
            const float cr = __shfl(corr, g4 + r);
            #pragma unroll
            for (int j = 0; j < 4; ++j) acc[j][r] *= cr;
        }
        #pragma unroll
        for (int j = 0; j < 4; ++j) {
            ushort4 w;
            w.x = f2b(pf_[j][0]); w.y = f2b(pf_[j][1]);
            w.z = f2b(pf_[j][2]); w.w = f2b(pf_[j][3]);
            *reinterpret_cast<ushort4*>(&Pl[wave][lr][j * 16 + g4]) = w;
        }
        #pragma unroll
        for (int kc = 0; kc < 64; kc += 32) {
            bf16x8 pa = *reinterpret_cast<const bf16x8*>(&Pl[wave][lr][kc + lk8]);
            #pragma unroll
            for (int j = 0; j < 4; ++j) {
                const int vrow = j * 16 + lr;
                bf16x8 vb = *reinterpret_cast<const bf16x8*>(
                    (const char*)Vt + (((vrow * 64 + kc + lk8) * 2) ^ ((vrow & 7) << 4)));
                acc[j] = __builtin_amdgcn_mfma_f32_16x16x32_bf16(pa, vb, acc[j], 0, 0, 0);
            }
        }
    }

    const float li = 1.f / lst;
    #pragma unroll
    for (int r = 0; r < 4; ++r) {
        const float lrc = __shfl(li, g4 + r);
        const int srow = s0 + wave * 16 + g4 + r;
        #pragma unroll
        for (int j = 0; j < 4; ++j) {
            ctx16[((size_t)b * S_LEN + srow) * DM + h * DKH + j * 16 + lr] =
                f2b(acc[j][r] * lrc);
        }
    }
}

// ---------------- row LayerNorm, optional bf16 copy ----------------
template <int EB16>
__global__ __launch_bounds__(256) void layernorm_kernel(
    const float* __restrict__ in, const float* __restrict__ gam, const float* __restrict__ bet,
    float* __restrict__ outf, unsigned short* __restrict__ outb) {
    __shared__ float red[8];
    const int row = blockIdx.x, t = threadIdx.x;
    const int wave = t >> 6, lane = t & 63;
    const float* p = in + (size_t)row * DM;
    const float v0 = p[t], v1 = p[t + 256], v2 = p[t + 512];
    float s = v0 + v1 + v2;
    float sq = v0 * v0 + v1 * v1 + v2 * v2;
    #pragma unroll
    for (int off = 32; off > 0; off >>= 1) { s += __shfl_xor(s, off); sq += __shfl_xor(sq, off); }
    if (lane == 0) { red[wave] = s; red[wave + 4] = sq; }
    __syncthreads();
    s = red[0] + red[1] + red[2] + red[3];
    sq = red[4] + red[5] + red[6] + red[7];
    const float mu = s * (1.f / DM);
    const float var = sq * (1.f / DM) - mu * mu;
    const float rs = rsqrtf(var + 1e-5f);
    #pragma unroll
    for (int i = 0; i < 3; ++i) {
        const int c = t + i * 256;
        const float vv = (i == 0 ? v0 : (i == 1 ? v1 : v2));
        const float y = (vv - mu) * rs * gam[c] + bet[c];
        outf[(size_t)row * DM + c] = y;
        if (EB16) outb[(size_t)row * DM + c] = f2b(y);
    }
}

extern "C" void kernel_launch(void* const* d_in, const int* in_sizes, int n_in,
                              void* d_out, int out_size, void* d_ws, size_t ws_size,
                              hipStream_t stream) {
    const float* x   = (const float*)d_in[0];
    const float* wq  = (const float*)d_in[1];
    const float* bq  = (const float*)d_in[2];
    const float* wk  = (const float*)d_in[3];
    const float* bk  = (const float*)d_in[4];
    const float* wv  = (const float*)d_in[5];
    const float* bv  = (const float*)d_in[6];
    const float* wo  = (const float*)d_in[7];
    const float* bo  = (const float*)d_in[8];
    const float* w1  = (const float*)d_in[9];
    const float* b1  = (const float*)d_in[10];
    const float* w2  = (const float*)d_in[11];
    const float* b2  = (const float*)d_in[12];
    const float* g1  = (const float*)d_in[13];
    const float* be1 = (const float*)d_in[14];
    const float* g2  = (const float*)d_in[15];
    const float* be2 = (const float*)d_in[16];

    char* wp = (char*)d_ws;
    auto alloc = [&](size_t bytes) -> void* {
        void* r = (void*)wp;
        wp += (bytes + 255) & ~(size_t)255;
        return r;
    };
    const int M = MROWS;
    unsigned short* wqkv16 = (unsigned short*)alloc((size_t)3 * DM * DM * 2);  // [2304][768]
    unsigned short* wo16 = (unsigned short*)alloc((size_t)DM * DM * 2);
    unsigned short* w116 = (unsigned short*)alloc((size_t)DM * DFF * 2);
    unsigned short* w216 = (unsigned short*)alloc((size_t)DM * DFF * 2);
    unsigned short* ctx16 = (unsigned short*)alloc((size_t)M * DM * 2);
    float* y1 = (float*)alloc((size_t)M * DM * 4);
    unsigned short* x16  = (unsigned short*)alloc((size_t)M * DM * 2);
    unsigned short* q16  = (unsigned short*)alloc((size_t)M * DM * 2);
    unsigned short* k16  = (unsigned short*)alloc((size_t)M * DM * 2);
    unsigned short* vt16 = (unsigned short*)alloc((size_t)M * DM * 2);
    unsigned short* ff116 = x16;    // [M,DFF] bf16 over x16..vt16 (contiguous, dead after QKV/attn)
    unsigned short* x116  = ctx16;  // LN1 bf16 output

    convert_bf16_kernel<<<(M * DM / 4 + 255) / 256, 256, 0, stream>>>(x, x16, M * DM / 4);
    transpose_bf16_kernel<<<dim3(DM / 32, DM / 32), 256, 0, stream>>>(wq, wqkv16, DM, DM);
    transpose_bf16_kernel<<<dim3(DM / 32, DM / 32), 256, 0, stream>>>(wk, wqkv16 + (size_t)DM * DM, DM, DM);
    transpose_bf16_kernel<<<dim3(DM / 32, DM / 32), 256, 0, stream>>>(wv, wqkv16 + (size_t)2 * DM * DM, DM, DM);
    transpose_bf16_kernel<<<dim3(DM / 32, DM / 32), 256, 0, stream>>>(wo, wo16, DM, DM);
    transpose_bf16_kernel<<<dim3(DFF / 32, DM / 32), 256, 0, stream>>>(w1, w116, DM, DFF);
    transpose_bf16_kernel<<<dim3(DM / 32, DFF / 32), 256, 0, stream>>>(w2, w216, DFF, DM);

    const float QSCALE = 0.125f * 1.44269504088896f;
    gemm128_qkv<<<dim3(3 * DM / 128, M / 128), 256, 0, stream>>>(
        x16, wqkv16, bq, bk, bv, q16, k16, vt16, M, 3 * DM, DM, QSCALE);

    attn_mfma_kernel<<<dim3(S_LEN / 64, BATCH * NH), 256, 0, stream>>>(q16, k16, vt16, ctx16);

    gemm128<0, 1, 1, 0><<<dim3(DM / 128, M / 128), 256, 0, stream>>>(
        ctx16, wo16, bo, x, y1, nullptr, M, DM, DM);
    layernorm_kernel<1><<<M, 256, 0, stream>>>(y1, g1, be1, y1, x116);

    gemm128<1, 0, 0, 1><<<dim3(DFF / 128, M / 128), 256, 0, stream>>>(
        x116, w116, b1, nullptr, nullptr, ff116, M, DFF, DM);
    gemm128<0, 1, 1, 0><<<dim3(DM / 128, M / 128), 256, 0, stream>>>(
        ff116, w216, b2, y1, (float*)d_out, nullptr, M, DM, DFF);
    layernorm_kernel<0><<<M, 256, 0, stream>>>((float*)d_out, g2, be2, (float*)d_out, nullptr);
}

// Round 4
// 292.295 us; speedup vs baseline: 3.7190x; 1.0424x over previous
//
#include <hip/hip_runtime.h>
#include <stdint.h>

#define S_LEN 2048
#define BATCH 2
#define DM 768
#define NH 12
#define DKH 64
#define DFF 3072
#define MROWS (BATCH * S_LEN)  // 4096

typedef short bf16x8 __attribute__((ext_vector_type(8)));
typedef float f32x4 __attribute__((ext_vector_type(4)));

__device__ __forceinline__ unsigned short f2b(float f) {
    union { float f; unsigned u; } cv; cv.f = f;
    unsigned u = cv.u;
    unsigned r = (u + 0x7FFFu + ((u >> 16) & 1u)) >> 16;  // RNE
    return (unsigned short)r;
}

__device__ __forceinline__ void gload16(const void* g, void* l) {
    __builtin_amdgcn_global_load_lds(
        (const __attribute__((address_space(1))) unsigned int*)g,
        (__attribute__((address_space(3))) unsigned int*)l, 16, 0, 0);
}

// ---------------- conversion: f32 -> bf16 (vectorized) ----------------
__global__ __launch_bounds__(256) void convert_bf16_kernel(
    const float* __restrict__ in, unsigned short* __restrict__ out, int n4) {
    int i = blockIdx.x * 256 + threadIdx.x;
    if (i < n4) {
        float4 v = reinterpret_cast<const float4*>(in)[i];
        ushort4 o;
        o.x = f2b(v.x); o.y = f2b(v.y); o.z = f2b(v.z); o.w = f2b(v.w);
        reinterpret_cast<ushort4*>(out)[i] = o;
    }
}

// ---------------- transpose + convert: W[R][C] f32 -> Wt[C][R] bf16 ----------------
__global__ __launch_bounds__(256) void transpose_bf16_kernel(
    const float* __restrict__ in, unsigned short* __restrict__ out, int R, int C) {
    __shared__ float tile[32][33];
    int c0 = blockIdx.x * 32, r0 = blockIdx.y * 32;
    int tx = threadIdx.x & 31, ty = threadIdx.x >> 5;  // 32 x 8
    #pragma unroll
    for (int i = ty; i < 32; i += 8)
        tile[i][tx] = in[(size_t)(r0 + i) * C + c0 + tx];
    __syncthreads();
    #pragma unroll
    for (int i = ty; i < 32; i += 8)
        out[(size_t)(c0 + i) * R + r0 + tx] = f2b(tile[tx][i]);
}

// ============ m97-structure GEMM: 128x128 tile, BK=64, global_load_lds staging ============
#define GEMM_STAGE(kt)                                                                   \
    {                                                                                    \
        const char* ga = (const char*)(A + (size_t)bm * K + ((kt) << 6));                \
        const char* gb = (const char*)(Bt + (size_t)bn * K + ((kt) << 6));               \
        const size_t K2 = (size_t)K * 2;                                                 \
        _Pragma("unroll")                                                                \
        for (int p = 0; p < 4; ++p)                                                      \
            gload16(ga + (size_t)(srow + p * 32) * K2 + scol,                            \
                    (char*)As + p * 4096 + t * 16);                                      \
        _Pragma("unroll")                                                                \
        for (int p = 0; p < 4; ++p)                                                      \
            gload16(gb + (size_t)(srow + p * 32) * K2 + scol,                            \
                    (char*)Bs + p * 4096 + t * 16);                                      \
    }

#define GEMM_COMPUTE()                                                                   \
    _Pragma("unroll")                                                                    \
    for (int ks = 0; ks < 64; ks += 32) {                                                \
        bf16x8 af[4], bfv[4];                                                            \
        _Pragma("unroll")                                                                \
        for (int i = 0; i < 4; ++i)                                                      \
            af[i] = *reinterpret_cast<const bf16x8*>(&As[(wrow * 64 + i * 16 + lr) * 64 + ks + lk8]); \
        _Pragma("unroll")                                                                \
        for (int j = 0; j < 4; ++j)                                                      \
            bfv[j] = *reinterpret_cast<const bf16x8*>(&Bs[(wcol * 64 + j * 16 + lr) * 64 + ks + lk8]); \
        _Pragma("unroll")                                                                \
        for (int i = 0; i < 4; ++i)                                                      \
            _Pragma("unroll")                                                            \
            for (int j = 0; j < 4; ++j)                                                  \
                acc[i][j] = __builtin_amdgcn_mfma_f32_16x16x32_bf16(af[i], bfv[j], acc[i][j], 0, 0, 0); \
    }

#define GEMM_PROLOG()                                                                    \
    __shared__ __align__(16) unsigned short As[128 * 64];                                \
    __shared__ __align__(16) unsigned short Bs[128 * 64];                                \
    const int t = threadIdx.x;                                                           \
    const int wave = t >> 6, lane = t & 63;                                              \
    const int wrow = wave >> 1, wcol = wave & 1;                                         \
    const int bn = blockIdx.x * 128, bm = blockIdx.y * 128;                              \
    const int lr = lane & 15;                                                            \
    const int lk8 = (lane >> 4) << 3;                                                    \
    const int srow = t >> 3;                                                             \
    const int scol = (t & 7) * 16;                                                       \
    f32x4 acc[4][4];                                                                     \
    _Pragma("unroll")                                                                    \
    for (int i = 0; i < 4; ++i)                                                          \
        _Pragma("unroll")                                                                \
        for (int j = 0; j < 4; ++j) { f32x4 z = {0.f, 0.f, 0.f, 0.f}; acc[i][j] = z; }   \
    const int nkt = K >> 6;                                                              \
    for (int kt = 0; kt < nkt; ++kt) {                                                   \
        GEMM_STAGE(kt)                                                                   \
        __syncthreads();                                                                 \
        GEMM_COMPUTE()                                                                   \
        __syncthreads();                                                                 \
    }                                                                                    \
    const int r0 = (lane >> 4) << 2;

template <int RELU, int RES, int EF32, int EB16>
__global__ __launch_bounds__(256) void gemm128(
    const unsigned short* __restrict__ A, const unsigned short* __restrict__ Bt,
    const float* __restrict__ bias, const float* __restrict__ res,
    float* __restrict__ outf, unsigned short* __restrict__ outb,
    int M, int N, int K) {
    GEMM_PROLOG()
    #pragma unroll
    for (int i = 0; i < 4; ++i) {
        const int row_b = bm + wrow * 64 + i * 16 + r0;
        #pragma unroll
        for (int j = 0; j < 4; ++j) {
            const int col = bn + wcol * 64 + j * 16 + lr;
            const float bvv = bias[col];
            #pragma unroll
            for (int r = 0; r < 4; ++r) {
                float vv = acc[i][j][r] + bvv;
                if (RES) vv += res[(size_t)(row_b + r) * N + col];
                if (RELU) vv = vv > 0.f ? vv : 0.f;
                if (EF32) outf[(size_t)(row_b + r) * N + col] = vv;
                if (EB16) outb[(size_t)(row_b + r) * N + col] = f2b(vv);
            }
        }
    }
}

// ============ BM=128 x BN=64 variant for N=768 GEMMs (grid fill) ============
template <int RELU, int RES, int EF32, int EB16>
__global__ __launch_bounds__(256) void gemm_bt64(
    const unsigned short* __restrict__ A, const unsigned short* __restrict__ Bt,
    const float* __restrict__ bias, const float* __restrict__ res,
    float* __restrict__ outf, unsigned short* __restrict__ outb,
    int M, int N, int K) {
    __shared__ __align__(16) unsigned short As[128 * 64];
    __shared__ __align__(16) unsigned short Bs[64 * 64];
    const int t = threadIdx.x;
    const int wave = t >> 6, lane = t & 63;
    const int bn = blockIdx.x * 64, bm = blockIdx.y * 128;
    const int lr = lane & 15;
    const int lk8 = (lane >> 4) << 3;
    const int srow = t >> 3;
    const int scol = (t & 7) * 16;
    f32x4 acc[2][4];
    #pragma unroll
    for (int i = 0; i < 2; ++i)
        #pragma unroll
        for (int j = 0; j < 4; ++j) { f32x4 z = {0.f, 0.f, 0.f, 0.f}; acc[i][j] = z; }
    const int nkt = K >> 6;
    for (int kt = 0; kt < nkt; ++kt) {
        const char* ga = (const char*)(A + (size_t)bm * K + (kt << 6));
        const char* gb = (const char*)(Bt + (size_t)bn * K + (kt << 6));
        const size_t K2 = (size_t)K * 2;
        #pragma unroll
        for (int p = 0; p < 4; ++p)
            gload16(ga + (size_t)(srow + p * 32) * K2 + scol, (char*)As + p * 4096 + t * 16);
        #pragma unroll
        for (int p = 0; p < 2; ++p)
            gload16(gb + (size_t)(srow + p * 32) * K2 + scol, (char*)Bs + p * 4096 + t * 16);
        __syncthreads();
        #pragma unroll
        for (int ks = 0; ks < 64; ks += 32) {
            bf16x8 af[2], bfv[4];
            #pragma unroll
            for (int i = 0; i < 2; ++i)
                af[i] = *reinterpret_cast<const bf16x8*>(&As[(wave * 32 + i * 16 + lr) * 64 + ks + lk8]);
            #pragma unroll
            for (int j = 0; j < 4; ++j)
                bfv[j] = *reinterpret_cast<const bf16x8*>(&Bs[(j * 16 + lr) * 64 + ks + lk8]);
            #pragma unroll
            for (int i = 0; i < 2; ++i)
                #pragma unroll
                for (int j = 0; j < 4; ++j)
                    acc[i][j] = __builtin_amdgcn_mfma_f32_16x16x32_bf16(af[i], bfv[j], acc[i][j], 0, 0, 0);
        }
        __syncthreads();
    }
    const int r0 = (lane >> 4) << 2;
    #pragma unroll
    for (int i = 0; i < 2; ++i) {
        const int row_b = bm + wave * 32 + i * 16 + r0;
        #pragma unroll
        for (int j = 0; j < 4; ++j) {
            const int col = bn + j * 16 + lr;
            const float bvv = bias[col];
            #pragma unroll
            for (int r = 0; r < 4; ++r) {
                float vv = acc[i][j][r] + bvv;
                if (RES) vv += res[(size_t)(row_b + r) * N + col];
                if (RELU) vv = vv > 0.f ? vv : 0.f;
                if (EF32) outf[(size_t)(row_b + r) * N + col] = vv;
                if (EB16) outb[(size_t)(row_b + r) * N + col] = f2b(vv);
            }
        }
    }
}

// fused QKV epilogue: N=2304 = [Q | K | V]; Q scaled, K plain -> [B,H,S,64]; V -> [B,H,64,S]
__global__ __launch_bounds__(256) void gemm128_qkv(
    const unsigned short* __restrict__ A, const unsigned short* __restrict__ Bt,
    const float* __restrict__ bq, const float* __restrict__ bk, const float* __restrict__ bv,
    unsigned short* __restrict__ q16, unsigned short* __restrict__ k16,
    unsigned short* __restrict__ vt16, int M, int N, int K, float qscale) {
    GEMM_PROLOG()
    #pragma unroll
    for (int i = 0; i < 4; ++i) {
        const int row_b = bm + wrow * 64 + i * 16 + r0;
        const int b = row_b >> 11, s = row_b & 2047;
        #pragma unroll
        for (int j = 0; j < 4; ++j) {
            const int col = bn + wcol * 64 + j * 16 + lr;
            const int sec = (col >= 2 * DM) ? 2 : (col >= DM ? 1 : 0);
            const int nc = col - sec * DM;
            const int h = nc >> 6, d = nc & 63;
            const float bvv = (sec == 0 ? bq : (sec == 1 ? bk : bv))[nc];
            if (sec == 2) {
                ushort4 w;
                w.x = f2b(acc[i][j][0] + bvv);
                w.y = f2b(acc[i][j][1] + bvv);
                w.z = f2b(acc[i][j][2] + bvv);
                w.w = f2b(acc[i][j][3] + bvv);
                *reinterpret_cast<ushort4*>(
                    vt16 + (((size_t)(b * NH + h) * DKH) + d) * S_LEN + s) = w;
            } else {
                const float sc = (sec == 0) ? qscale : 1.f;
                unsigned short* dst = (sec == 0) ? q16 : k16;
                #pragma unroll
                for (int r = 0; r < 4; ++r)
                    dst[(((size_t)(b * NH + h) * S_LEN) + s + r) * DKH + d] =
                        f2b((acc[i][j][r] + bvv) * sc);
            }
        }
    }
}

// ---------------- MFMA causal flash attention, 128 q-rows/block ----------------
// 4 waves x 32 q-rows (2 groups of 16). Q in regs. K/V: T14 async-split staging
// (global->reg during compute of tile t, reg->LDS after barrier). KV tile = 64.
#define ATTN_LOADT(kt)                                                                    \
    {                                                                                     \
        const uint4* kg = (const uint4*)(k16 + hbase + (((size_t)(kt)) << 6) * DKH);      \
        kreg0 = kg[t];                                                                    \
        kreg1 = kg[256 + t];                                                              \
        const char* gv = (const char*)(vt16 + hbase) + ((kt) << 7);                       \
        {                                                                                 \
            int o = t * 16; int d = o >> 7;                                               \
            vreg0 = *(const uint4*)(gv + (size_t)d * (S_LEN * 2) + (o & 127));            \
        }                                                                                 \
        {                                                                                 \
            int o = (256 + t) * 16; int d = o >> 7;                                       \
            vreg1 = *(const uint4*)(gv + (size_t)d * (S_LEN * 2) + (o & 127));            \
        }                                                                                 \
    }

__global__ __launch_bounds__(256) void attn_mfma_kernel(
    const unsigned short* __restrict__ q16,   // [B,H,S,64]
    const unsigned short* __restrict__ k16,   // [B,H,S,64]
    const unsigned short* __restrict__ vt16,  // [B,H,64,S]
    unsigned short* __restrict__ ctx16) {     // [B,S,DM]
    __shared__ __align__(16) unsigned short Ks[64 * 64];
    __shared__ __align__(16) unsigned short Vt[64 * 64];
    __shared__ __align__(16) unsigned short Pl[8][16][72];  // [wave*2+g][q=lr][key]
    const int t = threadIdx.x, wave = t >> 6, lane = t & 63;
    const int qb = (gridDim.x - 1) - blockIdx.x;  // heavy blocks first
    const int bh = blockIdx.y;
    const int b = bh / NH, h = bh % NH;
    const int s0 = qb << 7;
    const size_t hbase = (size_t)bh * S_LEN * DKH;
    const int lr = lane & 15;
    const int g4 = (lane >> 4) << 2;
    const int lk8 = (lane >> 4) << 3;

    // Q in registers (pre-scaled to exp2 domain by the QKV GEMM)
    bf16x8 qa[2][2];
    #pragma unroll
    for (int g = 0; g < 2; ++g) {
        const int sQ = s0 + wave * 32 + g * 16 + lr;
        #pragma unroll
        for (int ks = 0; ks < 2; ++ks)
            qa[g][ks] = *reinterpret_cast<const bf16x8*>(
                q16 + hbase + (size_t)sQ * DKH + ks * 32 + lk8);
    }

    float mst[2] = {-3e38f, -3e38f}, lst[2] = {0.f, 0.f};
    f32x4 acc[2][4];
    #pragma unroll
    for (int g = 0; g < 2; ++g)
        #pragma unroll
        for (int j = 0; j < 4; ++j) { f32x4 z = {0.f, 0.f, 0.f, 0.f}; acc[g][j] = z; }

    uint4 kreg0, kreg1, vreg0, vreg1;
    const int nt = 2 * qb + 2;
    ATTN_LOADT(0)
    for (int kt = 0; kt < nt; ++kt) {
        __syncthreads();  // prev tile's LDS reads complete
        // write staged regs -> LDS (swizzled: byte ^= ((row&7)<<4))
        {
            int o = t * 16;
            int sw = o ^ (((o >> 7) & 7) << 4);
            *(uint4*)((char*)Ks + sw) = kreg0;
            *(uint4*)((char*)Vt + sw) = vreg0;
            int o1 = (256 + t) * 16;
            int sw1 = o1 ^ (((o1 >> 7) & 7) << 4);
            *(uint4*)((char*)Ks + sw1) = kreg1;
            *(uint4*)((char*)Vt + sw1) = vreg1;
        }
        __syncthreads();
        if (kt + 1 < nt) ATTN_LOADT(kt + 1)  // in flight during compute

        // S^T = K * Q^T
        f32x4 sc[2][4];
        #pragma unroll
        for (int g = 0; g < 2; ++g)
            #pragma unroll
            for (int j = 0; j < 4; ++j) { f32x4 z = {0.f, 0.f, 0.f, 0.f}; sc[g][j] = z; }
        __builtin_amdgcn_s_setprio(1);
        #pragma unroll
        for (int ks = 0; ks < 2; ++ks) {
            #pragma unroll
            for (int j = 0; j < 4; ++j) {
                const int krow = j * 16 + lr;
                bf16x8 ka = *reinterpret_cast<const bf16x8*>(
                    (const char*)Ks + (((krow * 64 + ks * 32 + lk8) * 2) ^ ((krow & 7) << 4)));
                #pragma unroll
                for (int g = 0; g < 2; ++g)
                    sc[g][j] = __builtin_amdgcn_mfma_f32_16x16x32_bf16(ka, qa[g][ks], sc[g][j], 0, 0, 0);
            }
        }
        __builtin_amdgcn_s_setprio(0);

        // online softmax per group (exp2 domain)
        #pragma unroll
        for (int g = 0; g < 2; ++g) {
            const int qg = s0 + wave * 32 + g * 16 + lr;
            float tm = -3e38f;
            #pragma unroll
            for (int j = 0; j < 4; ++j)
                #pragma unroll
                for (int r = 0; r < 4; ++r) {
                    const int kg = (kt << 6) + j * 16 + g4 + r;
                    const float v = (kg <= qg) ? sc[g][j][r] : -3e38f;
                    sc[g][j][r] = v;
                    tm = fmaxf(tm, v);
                }
            tm = fmaxf(tm, __shfl_xor(tm, 16));
            tm = fmaxf(tm, __shfl_xor(tm, 32));
            const float mn = fmaxf(mst[g], tm);
            const float corr = exp2f(mst[g] - mn);
            float ts = 0.f;
            #pragma unroll
            for (int j = 0; j < 4; ++j)
                #pragma unroll
                for (int r = 0; r < 4; ++r) {
                    const float p = exp2f(sc[g][j][r] - mn);
                    sc[g][j][r] = p;
                    ts += p;
                }
            ts += __shfl_xor(ts, 16);
            ts += __shfl_xor(ts, 32);
            lst[g] = lst[g] * corr + ts;
            mst[g] = mn;
            #pragma unroll
            for (int r = 0; r < 4; ++r) {
                const float cr = __shfl(corr, g4 + r);
                #pragma unroll
                for (int j = 0; j < 4; ++j) acc[g][j][r] *= cr;
            }
            #pragma unroll
            for (int j = 0; j < 4; ++j) {
                ushort4 w;
                w.x = f2b(sc[g][j][0]); w.y = f2b(sc[g][j][1]);
                w.z = f2b(sc[g][j][2]); w.w = f2b(sc[g][j][3]);
                *reinterpret_cast<ushort4*>(&Pl[wave * 2 + g][lr][j * 16 + g4]) = w;
            }
        }

        // PV: out[q][d] += P[q][key] * Vt[d][key]^T
        __builtin_amdgcn_s_setprio(1);
        #pragma unroll
        for (int kc = 0; kc < 64; kc += 32) {
            bf16x8 pa[2];
            #pragma unroll
            for (int g = 0; g < 2; ++g)
                pa[g] = *reinterpret_cast<const bf16x8*>(&Pl[wave * 2 + g][lr][kc + lk8]);
            #pragma unroll
            for (int j = 0; j < 4; ++j) {
                const int vrow = j * 16 + lr;
                bf16x8 vb = *reinterpret_cast<const bf16x8*>(
                    (const char*)Vt + (((vrow * 64 + kc + lk8) * 2) ^ ((vrow & 7) << 4)));
                #pragma unroll
                for (int g = 0; g < 2; ++g)
                    acc[g][j] = __builtin_amdgcn_mfma_f32_16x16x32_bf16(pa[g], vb, acc[g][j], 0, 0, 0);
            }
        }
        __builtin_amdgcn_s_setprio(0);
    }

    #pragma unroll
    for (int g = 0; g < 2; ++g) {
        const float li = 1.f / lst[g];
        #pragma unroll
        for (int r = 0; r < 4; ++r) {
            const float lrc = __shfl(li, g4 + r);
            const int srow = s0 + wave * 32 + g * 16 + g4 + r;
            #pragma unroll
            for (int j = 0; j < 4; ++j) {
                ctx16[((size_t)b * S_LEN + srow) * DM + h * DKH + j * 16 + lr] =
                    f2b(acc[g][j][r] * lrc);
            }
        }
    }
}

// ---------------- row LayerNorm, optional bf16 copy ----------------
template <int EB16>
__global__ __launch_bounds__(256) void layernorm_kernel(
    const float* __restrict__ in, const float* __restrict__ gam, const float* __restrict__ bet,
    float* __restrict__ outf, unsigned short* __restrict__ outb) {
    __shared__ float red[8];
    const int row = blockIdx.x, t = threadIdx.x;
    const int wave = t >> 6, lane = t & 63;
    const float* p = in + (size_t)row * DM;
    const float v0 = p[t], v1 = p[t + 256], v2 = p[t + 512];
    float s = v0 + v1 + v2;
    float sq = v0 * v0 + v1 * v1 + v2 * v2;
    #pragma unroll
    for (int off = 32; off > 0; off >>= 1) { s += __shfl_xor(s, off); sq += __shfl_xor(sq, off); }
    if (lane == 0) { red[wave] = s; red[wave + 4] = sq; }
    __syncthreads();
    s = red[0] + red[1] + red[2] + red[3];
    sq = red[4] + red[5] + red[6] + red[7];
    const float mu = s * (1.f / DM);
    const float var = sq * (1.f / DM) - mu * mu;
    const float rs = rsqrtf(var + 1e-5f);
    #pragma unroll
    for (int i = 0; i < 3; ++i) {
        const int c = t + i * 256;
        const float vv = (i == 0 ? v0 : (i == 1 ? v1 : v2));
        const float y = (vv - mu) * rs * gam[c] + bet[c];
        outf[(size_t)row * DM + c] = y;
        if (EB16) outb[(size_t)row * DM + c] = f2b(y);
    }
}

extern "C" void kernel_launch(void* const* d_in, const int* in_sizes, int n_in,
                              void* d_out, int out_size, void* d_ws, size_t ws_size,
                              hipStream_t stream) {
    const float* x   = (const float*)d_in[0];
    const float* wq  = (const float*)d_in[1];
    const float* bq  = (const float*)d_in[2];
    const float* wk  = (const float*)d_in[3];
    const float* bk  = (const float*)d_in[4];
    const float* wv  = (const float*)d_in[5];
    const float* bv  = (const float*)d_in[6];
    const float* wo  = (const float*)d_in[7];
    const float* bo  = (const float*)d_in[8];
    const float* w1  = (const float*)d_in[9];
    const float* b1  = (const float*)d_in[10];
    const float* w2  = (const float*)d_in[11];
    const float* b2  = (const float*)d_in[12];
    const float* g1  = (const float*)d_in[13];
    const float* be1 = (const float*)d_in[14];
    const float* g2  = (const float*)d_in[15];
    const float* be2 = (const float*)d_in[16];

    char* wp = (char*)d_ws;
    auto alloc = [&](size_t bytes) -> void* {
        void* r = (void*)wp;
        wp += (bytes + 255) & ~(size_t)255;
        return r;
    };
    const int M = MROWS;
    unsigned short* wqkv16 = (unsigned short*)alloc((size_t)3 * DM * DM * 2);  // [2304][768]
    unsigned short* wo16 = (unsigned short*)alloc((size_t)DM * DM * 2);
    unsigned short* w116 = (unsigned short*)alloc((size_t)DM * DFF * 2);
    unsigned short* w216 = (unsigned short*)alloc((size_t)DM * DFF * 2);
    unsigned short* ctx16 = (unsigned short*)alloc((size_t)M * DM * 2);
    float* y1 = (float*)alloc((size_t)M * DM * 4);
    unsigned short* x16  = (unsigned short*)alloc((size_t)M * DM * 2);
    unsigned short* q16  = (unsigned short*)alloc((size_t)M * DM * 2);
    unsigned short* k16  = (unsigned short*)alloc((size_t)M * DM * 2);
    unsigned short* vt16 = (unsigned short*)alloc((size_t)M * DM * 2);
    unsigned short* ff116 = x16;    // [M,DFF] bf16 over x16..vt16 (contiguous, dead after QKV/attn)
    unsigned short* x116  = ctx16;  // LN1 bf16 output

    convert_bf16_kernel<<<(M * DM / 4 + 255) / 256, 256, 0, stream>>>(x, x16, M * DM / 4);
    transpose_bf16_kernel<<<dim3(DM / 32, DM / 32), 256, 0, stream>>>(wq, wqkv16, DM, DM);
    transpose_bf16_kernel<<<dim3(DM / 32, DM / 32), 256, 0, stream>>>(wk, wqkv16 + (size_t)DM * DM, DM, DM);
    transpose_bf16_kernel<<<dim3(DM / 32, DM / 32), 256, 0, stream>>>(wv, wqkv16 + (size_t)2 * DM * DM, DM, DM);
    transpose_bf16_kernel<<<dim3(DM / 32, DM / 32), 256, 0, stream>>>(wo, wo16, DM, DM);
    transpose_bf16_kernel<<<dim3(DFF / 32, DM / 32), 256, 0, stream>>>(w1, w116, DM, DFF);
    transpose_bf16_kernel<<<dim3(DM / 32, DFF / 32), 256, 0, stream>>>(w2, w216, DFF, DM);

    const float QSCALE = 0.125f * 1.44269504088896f;
    gemm128_qkv<<<dim3(3 * DM / 128, M / 128), 256, 0, stream>>>(
        x16, wqkv16, bq, bk, bv, q16, k16, vt16, M, 3 * DM, DM, QSCALE);

    attn_mfma_kernel<<<dim3(S_LEN / 128, BATCH * NH), 256, 0, stream>>>(q16, k16, vt16, ctx16);

    gemm_bt64<0, 1, 1, 0><<<dim3(DM / 64, M / 128), 256, 0, stream>>>(
        ctx16, wo16, bo, x, y1, nullptr, M, DM, DM);
    layernorm_kernel<1><<<M, 256, 0, stream>>>(y1, g1, be1, y1, x116);

    gemm128<1, 0, 0, 1><<<dim3(DFF / 128, M / 128), 256, 0, stream>>>(
        x116, w116, b1, nullptr, nullptr, ff116, M, DFF, DM);
    gemm_bt64<0, 1, 1, 0><<<dim3(DM / 64, M / 128), 256, 0, stream>>>(
        ff116, w216, b2, y1, (float*)d_out, nullptr, M, DM, DFF);
    layernorm_kernel<0><<<M, 256, 0, stream>>>((float*)d_out, g2, be2, (float*)d_out, nullptr);
}